// Round 4
// baseline (7615.424 us; speedup 1.0000x reference)
//
#include <hip/hip_runtime.h>
#include <hip/hip_bf16.h>
#include <stdint.h>

// Neural CDE, B=256 T=512 D=64 H=128 W=256.
// Round 4: persistent kernel, leader/follower split.
//  - 256 WGs = 8 groups (32 batch rows) x 32 HD-chunks; 1 WG/CU.
//  - 2 leader WGs per group compute stage A (gemm0+gemm1) for 16 rows each,
//    publish g1 via LLC + flag; all 32 WGs then run gemm2 for their 256 cols.
//  - flag-gated bulk exchange (relaxed agent atomics; __syncthreads drains
//    stores before flag store; monotone step-tag flags, 2-slot data ABA-safe).
//  - launch_bounds(512,1): 256-VGPR budget, w2 frags register-resident.
// dt = 1, frac = 0 for k<=510 => deriv = coeffs_b[:,k]; k=511 => b+2c+3d at idx 510.

#define BB 256
#define DD 64
#define HH 128
#define WW 256
#define HD 8192
#define TSTEPS 512
#define NGRP 8
#define GSZ 32
#define PAD_Y 152   // bf16 row stride for yb
#define PAD_G 280   // bf16 row stride for g0s/g1s (even -> u32 writes aligned)
#define PAD_DV 68   // f32 row stride for dv

typedef __bf16 bf16x8 __attribute__((ext_vector_type(8)));
typedef __bf16 bf16x4 __attribute__((ext_vector_type(4)));
typedef float f32x4 __attribute__((ext_vector_type(4)));

__device__ __forceinline__ float softplus_f(float x) {
  return (x > 15.f) ? x : __logf(1.f + __expf(x));
}
__device__ __forceinline__ float tanh_f(float x) {
  float e = __expf(2.f * x);
  return 1.f - 2.f / (e + 1.f);
}
__device__ __forceinline__ uint32_t pack_bf16x2(float a, float b) {
  unsigned short ua = __builtin_bit_cast(unsigned short, (__bf16)a);
  unsigned short ub = __builtin_bit_cast(unsigned short, (__bf16)b);
  return (uint32_t)ua | ((uint32_t)ub << 16);
}
__device__ __forceinline__ uint32_t aload(const uint32_t* p) {
  return __hip_atomic_load(p, __ATOMIC_RELAXED, __HIP_MEMORY_SCOPE_AGENT);
}
__device__ __forceinline__ void astore(uint32_t* p, uint32_t v) {
  __hip_atomic_store(p, v, __ATOMIC_RELAXED, __HIP_MEMORY_SCOPE_AGENT);
}

__global__ void prep_kernel(const float* __restrict__ w0, const float* __restrict__ w1,
                            const float* __restrict__ w2,
                            __bf16* __restrict__ w0b, __bf16* __restrict__ w1b,
                            __bf16* __restrict__ w2b) {
  int stride = gridDim.x * blockDim.x;
  int i0 = blockIdx.x * blockDim.x + threadIdx.x;
  for (int i = i0; i < WW * HH; i += stride) w0b[i] = (__bf16)w0[i];
  for (int i = i0; i < WW * WW; i += stride) w1b[i] = (__bf16)w1[i];
  for (int i = i0; i < HD * WW; i += stride) w2b[i] = (__bf16)w2[i];
}

__global__ __launch_bounds__(256) void init_kernel(
    const float* __restrict__ ca, const float* __restrict__ iw0, const float* __restrict__ ib0,
    const float* __restrict__ iw1, const float* __restrict__ ib1,
    const float* __restrict__ iw2, const float* __restrict__ ib2,
    float* __restrict__ y0) {
  __shared__ float x0[DD];
  __shared__ float h0[WW];
  __shared__ float h1[WW];
  int b = blockIdx.x, t = threadIdx.x;
  if (t < DD) x0[t] = ca[((size_t)b * 511) * DD + t];
  __syncthreads();
  float a = ib0[t];
  for (int d = 0; d < DD; ++d) a = fmaf(x0[d], iw0[t * DD + d], a);
  h0[t] = fmaxf(a, 0.f);
  __syncthreads();
  a = ib1[t];
  for (int d = 0; d < WW; ++d) a = fmaf(h0[d], iw1[t * WW + d], a);
  h1[t] = fmaxf(a, 0.f);
  __syncthreads();
  if (t < HH) {
    a = ib2[t];
    for (int d = 0; d < WW; ++d) a = fmaf(h1[d], iw2[t * WW + d], a);
    y0[b * HH + t] = a;
  }
}

// Persistent: 256 WGs x 512 threads, loops k=0..511.
__global__ __launch_bounds__(512, 1) void step_persist(
    const __bf16* __restrict__ w0b, const __bf16* __restrict__ w1b, const __bf16* __restrict__ w2b,
    const float* __restrict__ fb0, const float* __restrict__ fb1, const float* __restrict__ fb2,
    const float* __restrict__ cbp, const float* __restrict__ ccp, const float* __restrict__ cdp,
    float* __restrict__ yA, uint32_t* __restrict__ pky, uint32_t* __restrict__ pg,
    uint32_t* __restrict__ yflag, uint32_t* __restrict__ gflag)
{
  __shared__ __align__(16) __bf16 yb[16 * PAD_Y];
  __shared__ __align__(16) __bf16 g0s[16 * PAD_G];
  __shared__ __align__(16) __bf16 g1s[32 * PAD_G];
  __shared__ __align__(16) float dv[32 * PAD_DV];
  __shared__ float pbuf[8 * 32];

  const int tid = threadIdx.x;
  const int wv = tid >> 6;
  const int l = tid & 63;
  const int l16 = l & 15;
  const int lq = l >> 4;

  const int wid = blockIdx.x;
  const int grp = wid >> 5;
  const int j = wid & 31;
  const int jr = (j - 4 * grp) & 31;     // rotated role index (spreads leaders over XCDs)
  const bool isLeader = (jr < 2);
  const int rb = grp * 32;
  const int c0 = j * 256;

  // ---- w2 fragments + gemm2 bias: register-resident for the whole scan
  bf16x8 w2f[8][2];
  f32x4 b2r[2];
  #pragma unroll
  for (int c = 0; c < 2; ++c) {
    int col = wv * 32 + c * 16 + l16;
    #pragma unroll
    for (int kb = 0; kb < 8; ++kb)
      w2f[kb][c] = *(const bf16x8*)&w2b[(size_t)(c0 + col) * WW + kb * 32 + lq * 8];
    b2r[c] = *(const f32x4*)&fb2[c0 + wv * 32 + c * 16 + lq * 4];
  }

  // ---- strength-reduced coefficient pointers + last-step correction
  const float* pcb[4];
  float ex[4];
  #pragma unroll
  for (int q = 0; q < 4; ++q) {
    int i = tid + q * 512;
    int r = i >> 6, d = i & (DD - 1);
    size_t base = ((size_t)(rb + r) * 511) * DD + d;
    pcb[q] = cbp + base;
    ex[q] = 2.f * ccp[base + (size_t)510 * DD] + 3.f * cdp[base + (size_t)510 * DD];
  }

  // ---- register-resident state: tid<128 owns (row rb+(tid&31), h=4j+(tid>>5))
  float yreg = 0.f;
  int myidx = 0;
  if (tid < 128) {
    int r = tid & 31, hl = tid >> 5;
    myidx = (rb + r) * HH + (4 * j + hl);
    yreg = yA[myidx];
    astore(&pky[myidx], __builtin_bit_cast(uint32_t, yreg));   // slot 0 (tag 1)
  }
  __syncthreads();
  if (tid == 0) astore(&yflag[grp * GSZ + j], 1u);

  for (int k = 0; k < TSTEPS; ++k) {
    const uint32_t want = (uint32_t)(k + 1);

    // ---- deriv (strength-reduced) -> dv LDS
    #pragma unroll
    for (int q = 0; q < 4; ++q) {
      float v = *pcb[q];
      if (k < 510) pcb[q] += DD;
      if (k == 511) v += ex[q];
      int i = tid + q * 512;
      dv[(i >> 6) * PAD_DV + (i & (DD - 1))] = v;
    }

    uint32_t* pgs = pg + (size_t)(k & 1) * (NGRP * 4096) + grp * 4096;

    if (isLeader) {
      // issue w0/w1 frag + bias loads (in flight during flag poll)
      bf16x8 w0t[4][2], w1t[8][2];
      f32x4 b0r[2], b1r[2];
      #pragma unroll
      for (int c = 0; c < 2; ++c) {
        int col = wv * 32 + c * 16 + l16;
        #pragma unroll
        for (int kb = 0; kb < 4; ++kb)
          w0t[kb][c] = *(const bf16x8*)&w0b[col * HH + kb * 32 + lq * 8];
        #pragma unroll
        for (int kb = 0; kb < 8; ++kb)
          w1t[kb][c] = *(const bf16x8*)&w1b[col * WW + kb * 32 + lq * 8];
        b0r[c] = *(const f32x4*)&fb0[wv * 32 + c * 16 + lq * 4];
        b1r[c] = *(const f32x4*)&fb1[wv * 32 + c * 16 + lq * 4];
      }
      // poll all 32 y flags of this group
      {
        const uint32_t* yf = yflag + grp * GSZ + (l & 31);
        const bool need = (l < 32);
        int spins = 0;
        while (true) {
          uint32_t f = need ? aload(yf) : want;
          if (__all(f == want)) break;
          __builtin_amdgcn_s_sleep(1);
          if (++spins > (1 << 22)) break;
        }
      }
      __asm__ __volatile__("" ::: "memory");
      // bulk-read y (16 rows x 128 h, f32 words) -> bf16 LDS
      {
        const uint32_t* ysl = pky + (size_t)(k & 1) * (BB * HH);
        #pragma unroll
        for (int q = 0; q < 4; ++q) {
          int i = tid + q * 512;
          int rl = i >> 7, h = i & (HH - 1);
          uint32_t w = aload(&ysl[(rb + 16 * jr + rl) * HH + h]);
          yb[rl * PAD_Y + h] = (__bf16)__builtin_bit_cast(float, w);
        }
      }
      __syncthreads();
      // gemm0: 16 rows, out 256 cols
      {
        f32x4 acc[2] = {};
        #pragma unroll
        for (int kb = 0; kb < 4; ++kb) {
          bf16x8 yf8 = *(const bf16x8*)&yb[l16 * PAD_Y + kb * 32 + lq * 8];
          #pragma unroll
          for (int c = 0; c < 2; ++c)
            acc[c] = __builtin_amdgcn_mfma_f32_16x16x32_bf16(w0t[kb][c], yf8, acc[c], 0, 0, 0);
        }
        #pragma unroll
        for (int c = 0; c < 2; ++c) {
          bf16x4 o;
          #pragma unroll
          for (int r = 0; r < 4; ++r)
            o[r] = (__bf16)softplus_f(acc[c][r] + b0r[c][r]);
          *(bf16x4*)&g0s[l16 * PAD_G + wv * 32 + c * 16 + lq * 4] = o;
        }
      }
      __syncthreads();
      // gemm1 + publish g1 slice (rows 16*jr..+15)
      {
        f32x4 acc[2] = {};
        #pragma unroll
        for (int kb = 0; kb < 8; ++kb) {
          bf16x8 a8 = *(const bf16x8*)&g0s[l16 * PAD_G + kb * 32 + lq * 8];
          #pragma unroll
          for (int c = 0; c < 2; ++c)
            acc[c] = __builtin_amdgcn_mfma_f32_16x16x32_bf16(w1t[kb][c], a8, acc[c], 0, 0, 0);
        }
        int gr = 16 * jr + l16;
        #pragma unroll
        for (int c = 0; c < 2; ++c) {
          float v0 = softplus_f(acc[c][0] + b1r[c][0]);
          float v1 = softplus_f(acc[c][1] + b1r[c][1]);
          float v2 = softplus_f(acc[c][2] + b1r[c][2]);
          float v3 = softplus_f(acc[c][3] + b1r[c][3]);
          int p = wv * 16 + c * 8 + lq * 2;
          astore(&pgs[gr * 128 + p], pack_bf16x2(v0, v1));
          astore(&pgs[gr * 128 + p + 1], pack_bf16x2(v2, v3));
        }
      }
      __syncthreads();   // drain all waves' g1 stores to coherence point
      if (tid == 0) astore(&gflag[grp * 2 + jr], want);
    }

    // ---- all WGs: poll 2 g-flags, bulk-read g1
    {
      const uint32_t* gf = gflag + grp * 2 + (l & 1);
      const bool need = (l < 2);
      int spins = 0;
      while (true) {
        uint32_t f = need ? aload(gf) : want;
        if (__all(f == want)) break;
        __builtin_amdgcn_s_sleep(2);
        if (++spins > (1 << 22)) break;
      }
    }
    __asm__ __volatile__("" ::: "memory");
    #pragma unroll
    for (int q = 0; q < 8; ++q) {
      int i = tid + q * 512;
      int row = i >> 7, p = i & 127;
      uint32_t w = aload(&pgs[row * 128 + p]);
      *(uint32_t*)&g1s[row * PAD_G + 2 * p] = w;
    }
    __syncthreads();

    // ---- gemm2 chunk + tanh + d-contraction
    {
      f32x4 acc[2][2] = {};
      #pragma unroll
      for (int kb = 0; kb < 8; ++kb) {
        bf16x8 a0 = *(const bf16x8*)&g1s[l16 * PAD_G + kb * 32 + lq * 8];
        bf16x8 a1 = *(const bf16x8*)&g1s[(16 + l16) * PAD_G + kb * 32 + lq * 8];
        #pragma unroll
        for (int c = 0; c < 2; ++c) {
          acc[c][0] = __builtin_amdgcn_mfma_f32_16x16x32_bf16(w2f[kb][c], a0, acc[c][0], 0, 0, 0);
          acc[c][1] = __builtin_amdgcn_mfma_f32_16x16x32_bf16(w2f[kb][c], a1, acc[c][1], 0, 0, 0);
        }
      }
      #pragma unroll
      for (int bt = 0; bt < 2; ++bt) {
        float p = 0.f;
        #pragma unroll
        for (int c = 0; c < 2; ++c) {
          f32x4 dvv = *(const f32x4*)&dv[(bt * 16 + l16) * PAD_DV +
                                         (wv & 1) * 32 + c * 16 + lq * 4];
          #pragma unroll
          for (int r = 0; r < 4; ++r) {
            float f = tanh_f(acc[c][bt][r] + b2r[c][r]);
            p = fmaf(f, dvv[r], p);
          }
        }
        p += __shfl_xor(p, 16);
        p += __shfl_xor(p, 32);
        if (l < 16) pbuf[wv * 32 + bt * 16 + l] = p;
      }
    }
    __syncthreads();

    // ---- combine wave pairs, update state, publish y + flag
    if (tid < 128) {
      int hl = tid >> 5, r = tid & 31;
      yreg += pbuf[(2 * hl) * 32 + r] + pbuf[(2 * hl + 1) * 32 + r];
      uint32_t* ydst = pky + (size_t)((k + 1) & 1) * (BB * HH);
      astore(&ydst[myidx], __builtin_bit_cast(uint32_t, yreg));
    }
    __syncthreads();   // drain y stores
    if (tid == 0) astore(&yflag[grp * GSZ + j], (uint32_t)(k + 2));
  }

  if (tid < 128) yA[myidx] = yreg;
}

__global__ __launch_bounds__(256) void final_kernel(const float* __restrict__ y,
                                                    const float* __restrict__ lw,
                                                    const float* __restrict__ lb,
                                                    float* __restrict__ out) {
  int b = threadIdx.x;
  float a = lb[0];
  for (int h = 0; h < HH; ++h) a = fmaf(y[b * HH + h], lw[h], a);
  out[b] = 1.f / (1.f + __expf(-a));
}

extern "C" void kernel_launch(void* const* d_in, const int* in_sizes, int n_in,
                              void* d_out, int out_size, void* d_ws, size_t ws_size,
                              hipStream_t stream) {
  const float* cdp = (const float*)d_in[1];
  const float* ccp = (const float*)d_in[2];
  const float* cbp = (const float*)d_in[3];
  const float* cap = (const float*)d_in[4];
  const float* iw0 = (const float*)d_in[5];
  const float* ib0 = (const float*)d_in[6];
  const float* iw1 = (const float*)d_in[7];
  const float* ib1 = (const float*)d_in[8];
  const float* iw2 = (const float*)d_in[9];
  const float* ib2 = (const float*)d_in[10];
  const float* fw0 = (const float*)d_in[11];
  const float* fb0 = (const float*)d_in[12];
  const float* fw1 = (const float*)d_in[13];
  const float* fb1 = (const float*)d_in[14];
  const float* fw2 = (const float*)d_in[15];
  const float* fb2 = (const float*)d_in[16];
  const float* lw  = (const float*)d_in[17];
  const float* lb  = (const float*)d_in[18];

  char* ws = (char*)d_ws;
  __bf16* w0b = (__bf16*)(ws);                        // 64 KB
  __bf16* w1b = (__bf16*)(ws + 65536);                // 128 KB
  __bf16* w2b = (__bf16*)(ws + 196608);               // 4 MB
  float* yA = (float*)(ws + 4390912);                 // 128 KB
  uint32_t* pky = (uint32_t*)(ws + 4521984);          // 256 KB (2 slots)
  uint32_t* pg  = (uint32_t*)(ws + 4784128);          // 256 KB (2 slots)
  uint32_t* yflag = (uint32_t*)(ws + 5046272);        // 1 KB
  uint32_t* gflag = (uint32_t*)(ws + 5047296);        // 64 B

  hipMemsetAsync(yflag, 0, 2048, stream);             // yflag + gflag
  prep_kernel<<<512, 256, 0, stream>>>(fw0, fw1, fw2, w0b, w1b, w2b);
  init_kernel<<<BB, 256, 0, stream>>>(cap, iw0, ib0, iw1, ib1, iw2, ib2, yA);
  step_persist<<<256, 512, 0, stream>>>(w0b, w1b, w2b, fb0, fb1, fb2,
                                        cbp, ccp, cdp, yA, pky, pg, yflag, gflag);
  final_kernel<<<1, 256, 0, stream>>>(yA, lw, lb, (float*)d_out);

  (void)in_sizes; (void)n_in; (void)out_size; (void)ws_size;
}

// Round 5
// 4767.080 us; speedup vs baseline: 1.5975x; 1.5975x over previous
//
#include <hip/hip_runtime.h>
#include <hip/hip_bf16.h>
#include <stdint.h>

// Neural CDE, B=256 T=512 D=64 H=128 W=256.
// Round 5: round-3 topology (redundant stage A, tagged bf16 push-exchange)
//          + FORCED register residency of all weight fragments.
//  - 256 WGs = 8 groups (32 batch rows) x 32 HD-chunks; 1 WG/CU, 8 waves.
//  - 40 bf16x8 weight frags/thread pinned in VGPRs via empty-asm (non-remat).
//  - f32 state in registers of owning WG; published as (tag16|bf16) words.
// dt = 1, frac = 0 for k<=510 => deriv = coeffs_b[:,k]; k=511 => b+2c+3d at idx 510.

#define BB 256
#define DD 64
#define HH 128
#define WW 256
#define HD 8192
#define TSTEPS 512
#define PAD_Y 152   // bf16 row stride for yb
#define PAD_G 280   // bf16 row stride for g0s/g1s
#define PAD_DV 68   // f32 row stride for dv

typedef __bf16 bf16x8 __attribute__((ext_vector_type(8)));
typedef __bf16 bf16x4 __attribute__((ext_vector_type(4)));
typedef float f32x4 __attribute__((ext_vector_type(4)));

// Non-rematerializable pin: forces the value to stay in VGPRs across the loop.
#define PINV(x) asm volatile("" : "+v"(x))

__device__ __forceinline__ float softplus_f(float x) {
  return (x > 15.f) ? x : __logf(1.f + __expf(x));
}
__device__ __forceinline__ float tanh_f(float x) {
  float e = __expf(2.f * x);
  return 1.f - 2.f / (e + 1.f);
}

__device__ __forceinline__ void publish_y(uint32_t* slot, int idx, float val, uint32_t tag) {
  unsigned short ub = __builtin_bit_cast(unsigned short, (__bf16)val);
  __hip_atomic_store(&slot[idx], (tag << 16) | (uint32_t)ub,
                     __ATOMIC_RELAXED, __HIP_MEMORY_SCOPE_AGENT);
}

__global__ void prep_kernel(const float* __restrict__ w0, const float* __restrict__ w1,
                            const float* __restrict__ w2,
                            __bf16* __restrict__ w0b, __bf16* __restrict__ w1b,
                            __bf16* __restrict__ w2b) {
  int stride = gridDim.x * blockDim.x;
  int i0 = blockIdx.x * blockDim.x + threadIdx.x;
  for (int i = i0; i < WW * HH; i += stride) w0b[i] = (__bf16)w0[i];
  for (int i = i0; i < WW * WW; i += stride) w1b[i] = (__bf16)w1[i];
  for (int i = i0; i < HD * WW; i += stride) w2b[i] = (__bf16)w2[i];
}

// y0 = MLP(coeffs_a[:,0,:]) in plain f32 (one-off, tiny)
__global__ __launch_bounds__(256) void init_kernel(
    const float* __restrict__ ca, const float* __restrict__ iw0, const float* __restrict__ ib0,
    const float* __restrict__ iw1, const float* __restrict__ ib1,
    const float* __restrict__ iw2, const float* __restrict__ ib2,
    float* __restrict__ y0) {
  __shared__ float x0[DD];
  __shared__ float h0[WW];
  __shared__ float h1[WW];
  int b = blockIdx.x, t = threadIdx.x;
  if (t < DD) x0[t] = ca[((size_t)b * 511) * DD + t];
  __syncthreads();
  float a = ib0[t];
  for (int d = 0; d < DD; ++d) a = fmaf(x0[d], iw0[t * DD + d], a);
  h0[t] = fmaxf(a, 0.f);
  __syncthreads();
  a = ib1[t];
  for (int d = 0; d < WW; ++d) a = fmaf(h0[d], iw1[t * WW + d], a);
  h1[t] = fmaxf(a, 0.f);
  __syncthreads();
  if (t < HH) {
    a = ib2[t];
    for (int d = 0; d < WW; ++d) a = fmaf(h1[d], iw2[t * WW + d], a);
    y0[b * HH + t] = a;
  }
}

// Persistent step kernel: 256 WGs x 512 threads, loops k=0..511 internally.
__global__ __launch_bounds__(512, 2) void step_persist(
    const __bf16* __restrict__ w0b, const __bf16* __restrict__ w1b, const __bf16* __restrict__ w2b,
    const float* __restrict__ fb0, const float* __restrict__ fb1, const float* __restrict__ fb2,
    const float* __restrict__ cbp, const float* __restrict__ ccp, const float* __restrict__ cdp,
    float* __restrict__ yA, uint32_t* __restrict__ pk)
{
  __shared__ __align__(16) __bf16 yb[32 * PAD_Y];
  __shared__ __align__(16) __bf16 g0s[32 * PAD_G];
  __shared__ __align__(16) __bf16 g1s[32 * PAD_G];
  __shared__ __align__(16) float dv[32 * PAD_DV];
  __shared__ float pbuf[8 * 32];

  const int tid = threadIdx.x;
  const int wv = tid >> 6;
  const int l = tid & 63;
  const int l16 = l & 15;
  const int lq = l >> 4;

  const int wid = blockIdx.x;
  const int grp = wid >> 5;
  const int j = wid & 31;
  const int rb = grp * 32;   // batch row base
  const int c0 = j * 256;    // HD col base

  // ---- loop-invariant weight fragments (A-operand role: lane l16 <-> weight col)
  bf16x8 w0f[4][2], w1f[8][2], w2f[8][2];
  #pragma unroll
  for (int c = 0; c < 2; ++c) {
    int col = wv * 32 + c * 16 + l16;
    #pragma unroll
    for (int kb = 0; kb < 4; ++kb)
      w0f[kb][c] = *(const bf16x8*)&w0b[col * HH + kb * 32 + lq * 8];
    #pragma unroll
    for (int kb = 0; kb < 8; ++kb)
      w1f[kb][c] = *(const bf16x8*)&w1b[col * WW + kb * 32 + lq * 8];
    #pragma unroll
    for (int kb = 0; kb < 8; ++kb)
      w2f[kb][c] = *(const bf16x8*)&w2b[(size_t)(c0 + col) * WW + kb * 32 + lq * 8];
  }
  // biases per output col-quad (reg dim): float4 at col = wv*32 + c*16 + lq*4
  f32x4 b0r[2], b1r[2], b2r[2];
  #pragma unroll
  for (int c = 0; c < 2; ++c) {
    b0r[c] = *(const f32x4*)&fb0[wv * 32 + c * 16 + lq * 4];
    b1r[c] = *(const f32x4*)&fb1[wv * 32 + c * 16 + lq * 4];
    b2r[c] = *(const f32x4*)&fb2[c0 + wv * 32 + c * 16 + lq * 4];
  }
  // ---- PIN everything loop-invariant into VGPRs (blocks rematerialization)
  #pragma unroll
  for (int c = 0; c < 2; ++c) {
    #pragma unroll
    for (int kb = 0; kb < 4; ++kb) PINV(w0f[kb][c]);
    #pragma unroll
    for (int kb = 0; kb < 8; ++kb) PINV(w1f[kb][c]);
    #pragma unroll
    for (int kb = 0; kb < 8; ++kb) PINV(w2f[kb][c]);
    PINV(b0r[c]); PINV(b1r[c]); PINV(b2r[c]);
  }

  // ---- coefficient addressing (offset-based) + last-step correction
  int cbase[4];
  float ex[4];
  #pragma unroll
  for (int q = 0; q < 4; ++q) {
    int i = tid + q * 512;
    int r = i >> 6, d = i & (DD - 1);
    cbase[q] = ((rb + r) * 511) * DD + d;
    ex[q] = 2.f * ccp[cbase[q] + 510 * DD] + 3.f * cdp[cbase[q] + 510 * DD];
  }

  // ---- register-resident f32 state: tid<128 owns (row rb+(tid&31), h = 4j+(tid>>5))
  float yreg = 0.f;
  int myidx = 0;
  if (tid < 128) {
    int r = tid & 31, hl = tid >> 5;
    myidx = (rb + r) * HH + (4 * j + hl);
    yreg = yA[myidx];
    publish_y(pk, myidx, yreg, 1u);   // S_0 -> slot 0, tag 1
  }

  for (int k = 0; k < TSTEPS; ++k) {
    const uint32_t want = (uint32_t)(k + 1);
    const uint32_t* src = pk + (size_t)(k & 1) * (BB * HH);

    // ---- deriv loads into regs early
    float dreg[4];
    {
      int kk = (k <= 510) ? k : 510;
      #pragma unroll
      for (int q = 0; q < 4; ++q) {
        float v = cbp[cbase[q] + kk * DD];
        if (k == 511) v += ex[q];
        dreg[q] = v;
      }
    }

    // ---- poll + stage peers' y (tagged bf16 words)
    {
      uint32_t v[8];
      int ad[8];
      #pragma unroll
      for (int q = 0; q < 8; ++q) {
        int i = tid + q * 512;
        ad[q] = (rb + (i >> 7)) * HH + (i & (HH - 1));
        v[q] = __hip_atomic_load(&src[ad[q]], __ATOMIC_RELAXED, __HIP_MEMORY_SCOPE_AGENT);
      }
      int spins = 0;
      bool allok;
      do {
        allok = true;
        #pragma unroll
        for (int q = 0; q < 8; ++q) {
          if ((v[q] >> 16) != want) {
            allok = false;
            v[q] = __hip_atomic_load(&src[ad[q]], __ATOMIC_RELAXED, __HIP_MEMORY_SCOPE_AGENT);
          }
        }
        if (!allok) {
          __builtin_amdgcn_s_sleep(1);
          if (++spins > (1 << 20)) break;   // structurally impossible; bail visibly
        }
      } while (!allok);
      #pragma unroll
      for (int q = 0; q < 8; ++q) {
        int i = tid + q * 512;
        yb[(i >> 7) * PAD_Y + (i & (HH - 1))] =
            __builtin_bit_cast(__bf16, (unsigned short)(v[q] & 0xFFFFu));
      }
    }
    __syncthreads();

    // ---- gemm0 (swapped): D[w0col, brow] = w0 . y
    {
      f32x4 acc[2][2] = {};
      #pragma unroll
      for (int kb = 0; kb < 4; ++kb) {
        bf16x8 y0 = *(const bf16x8*)&yb[l16 * PAD_Y + kb * 32 + lq * 8];
        bf16x8 y1 = *(const bf16x8*)&yb[(16 + l16) * PAD_Y + kb * 32 + lq * 8];
        #pragma unroll
        for (int c = 0; c < 2; ++c) {
          acc[c][0] = __builtin_amdgcn_mfma_f32_16x16x32_bf16(w0f[kb][c], y0, acc[c][0], 0, 0, 0);
          acc[c][1] = __builtin_amdgcn_mfma_f32_16x16x32_bf16(w0f[kb][c], y1, acc[c][1], 0, 0, 0);
        }
      }
      #pragma unroll
      for (int c = 0; c < 2; ++c)
        #pragma unroll
        for (int bt = 0; bt < 2; ++bt) {
          bf16x4 o;
          #pragma unroll
          for (int r = 0; r < 4; ++r)
            o[r] = (__bf16)softplus_f(acc[c][bt][r] + b0r[c][r]);
          *(bf16x4*)&g0s[(bt * 16 + l16) * PAD_G + wv * 32 + c * 16 + lq * 4] = o;
        }
    }
    // dv regs -> LDS (read in gemm2 after barrier 3)
    #pragma unroll
    for (int q = 0; q < 4; ++q) {
      int i = tid + q * 512;
      dv[(i >> 6) * PAD_DV + (i & (DD - 1))] = dreg[q];
    }
    __syncthreads();

    // ---- gemm1 (swapped): D[w1col, brow] = w1 . g0
    {
      f32x4 acc[2][2] = {};
      #pragma unroll
      for (int kb = 0; kb < 8; ++kb) {
        bf16x8 a0 = *(const bf16x8*)&g0s[l16 * PAD_G + kb * 32 + lq * 8];
        bf16x8 a1 = *(const bf16x8*)&g0s[(16 + l16) * PAD_G + kb * 32 + lq * 8];
        #pragma unroll
        for (int c = 0; c < 2; ++c) {
          acc[c][0] = __builtin_amdgcn_mfma_f32_16x16x32_bf16(w1f[kb][c], a0, acc[c][0], 0, 0, 0);
          acc[c][1] = __builtin_amdgcn_mfma_f32_16x16x32_bf16(w1f[kb][c], a1, acc[c][1], 0, 0, 0);
        }
      }
      #pragma unroll
      for (int c = 0; c < 2; ++c)
        #pragma unroll
        for (int bt = 0; bt < 2; ++bt) {
          bf16x4 o;
          #pragma unroll
          for (int r = 0; r < 4; ++r)
            o[r] = (__bf16)softplus_f(acc[c][bt][r] + b1r[c][r]);
          *(bf16x4*)&g1s[(bt * 16 + l16) * PAD_G + wv * 32 + c * 16 + lq * 4] = o;
        }
    }
    __syncthreads();

    // ---- gemm2 chunk (swapped) + tanh + d-contraction
    {
      f32x4 acc[2][2] = {};
      #pragma unroll
      for (int kb = 0; kb < 8; ++kb) {
        bf16x8 a0 = *(const bf16x8*)&g1s[l16 * PAD_G + kb * 32 + lq * 8];
        bf16x8 a1 = *(const bf16x8*)&g1s[(16 + l16) * PAD_G + kb * 32 + lq * 8];
        #pragma unroll
        for (int c = 0; c < 2; ++c) {
          acc[c][0] = __builtin_amdgcn_mfma_f32_16x16x32_bf16(w2f[kb][c], a0, acc[c][0], 0, 0, 0);
          acc[c][1] = __builtin_amdgcn_mfma_f32_16x16x32_bf16(w2f[kb][c], a1, acc[c][1], 0, 0, 0);
        }
      }
      // lane holds: batch row = bt*16+l16; d = (wv&1)*32 + c*16 + lq*4 + r
      #pragma unroll
      for (int bt = 0; bt < 2; ++bt) {
        float p = 0.f;
        #pragma unroll
        for (int c = 0; c < 2; ++c) {
          f32x4 dvv = *(const f32x4*)&dv[(bt * 16 + l16) * PAD_DV +
                                         (wv & 1) * 32 + c * 16 + lq * 4];
          #pragma unroll
          for (int r = 0; r < 4; ++r) {
            float f = tanh_f(acc[c][bt][r] + b2r[c][r]);
            p = fmaf(f, dvv[r], p);
          }
        }
        p += __shfl_xor(p, 16);
        p += __shfl_xor(p, 32);
        if (l < 16) pbuf[wv * 32 + bt * 16 + l] = p;
      }
    }
    __syncthreads();

    // ---- combine wave pairs (d halves), update register state, publish
    if (tid < 128) {
      int hl = tid >> 5, r = tid & 31;
      yreg += pbuf[(2 * hl) * 32 + r] + pbuf[(2 * hl + 1) * 32 + r];
      publish_y(pk + (size_t)((k + 1) & 1) * (BB * HH), myidx, yreg, (uint32_t)(k + 2));
    }
    __syncthreads();
  }

  // final f32 state -> yA (kernel-end flush makes it visible to final_kernel)
  if (tid < 128) yA[myidx] = yreg;
}

__global__ __launch_bounds__(256) void final_kernel(const float* __restrict__ y,
                                                    const float* __restrict__ lw,
                                                    const float* __restrict__ lb,
                                                    float* __restrict__ out) {
  int b = threadIdx.x;
  float a = lb[0];
  for (int h = 0; h < HH; ++h) a = fmaf(y[b * HH + h], lw[h], a);
  out[b] = 1.f / (1.f + __expf(-a));
}

extern "C" void kernel_launch(void* const* d_in, const int* in_sizes, int n_in,
                              void* d_out, int out_size, void* d_ws, size_t ws_size,
                              hipStream_t stream) {
  const float* cdp = (const float*)d_in[1];
  const float* ccp = (const float*)d_in[2];
  const float* cbp = (const float*)d_in[3];
  const float* cap = (const float*)d_in[4];
  const float* iw0 = (const float*)d_in[5];
  const float* ib0 = (const float*)d_in[6];
  const float* iw1 = (const float*)d_in[7];
  const float* ib1 = (const float*)d_in[8];
  const float* iw2 = (const float*)d_in[9];
  const float* ib2 = (const float*)d_in[10];
  const float* fw0 = (const float*)d_in[11];
  const float* fb0 = (const float*)d_in[12];
  const float* fw1 = (const float*)d_in[13];
  const float* fb1 = (const float*)d_in[14];
  const float* fw2 = (const float*)d_in[15];
  const float* fb2 = (const float*)d_in[16];
  const float* lw  = (const float*)d_in[17];
  const float* lb  = (const float*)d_in[18];

  char* ws = (char*)d_ws;
  __bf16* w0b = (__bf16*)(ws);                              // 64 KB
  __bf16* w1b = (__bf16*)(ws + 65536);                      // 128 KB
  __bf16* w2b = (__bf16*)(ws + 65536 + 131072);             // 4 MB
  float* yA = (float*)(ws + 65536 + 131072 + 4194304);      // 128 KB
  uint32_t* pk = (uint32_t*)(ws + 65536 + 131072 + 4194304 + 131072);  // 256 KB (2 slots)

  hipMemsetAsync(pk, 0, 2 * BB * HH * sizeof(uint32_t), stream);
  prep_kernel<<<512, 256, 0, stream>>>(fw0, fw1, fw2, w0b, w1b, w2b);
  init_kernel<<<BB, 256, 0, stream>>>(cap, iw0, ib0, iw1, ib1, iw2, ib2, yA);
  step_persist<<<256, 512, 0, stream>>>(w0b, w1b, w2b, fb0, fb1, fb2,
                                        cbp, ccp, cdp, yA, pk);
  final_kernel<<<1, 256, 0, stream>>>(yA, lw, lb, (float*)d_out);

  (void)in_sizes; (void)n_in; (void)out_size; (void)ws_size;
}

// Round 6
// 4361.240 us; speedup vs baseline: 1.7462x; 1.0931x over previous
//
#include <hip/hip_runtime.h>
#include <hip/hip_bf16.h>
#include <stdint.h>

// Neural CDE, B=256 T=512 D=64 H=128 W=256.
// Round 6: r3 topology (redundant stage A, tagged bf16 push-exchange) +
//  - w2 chunk LDS-resident (128 KB, loaded once; conflict-free [kq][col][8] layout)
//  - w0/w1 prefetched into regs per step BEFORE the poll (latency hidden)
//  - amdgpu_waves_per_eu(2,2): unlocks >128 VGPR at our fixed 8-wave/CU occupancy
//  - dv via direct per-thread float4 global loads (dv LDS dropped)
//  - g0/g1 aliased into one LDS buffer (fits 154 KB total dynamic LDS)
// dt = 1, frac = 0 for k<=510 => deriv = coeffs_b[:,k]; k=511 => b+2c+3d at idx 510.

#define BB 256
#define DD 64
#define HH 128
#define WW 256
#define HD 8192
#define TSTEPS 512
#define PAD_Y 136   // bf16 row stride for yb (272 B => 2-way bank alias, free)
#define PAD_G 264   // bf16 row stride for g (528 B => 2-way, free)

#define SM_W2   0
#define SM_YB   131072
#define SM_G    140288   // 131072 + 32*136*2(=8704) = 139776 -> round to 140288 (16B align)
#define SM_PBUF 157184   // 140288 + 32*264*2(=16896) = 157184
#define SM_TOT  158208   // + 1024

typedef __bf16 bf16x8 __attribute__((ext_vector_type(8)));
typedef __bf16 bf16x4 __attribute__((ext_vector_type(4)));
typedef float f32x4 __attribute__((ext_vector_type(4)));

__device__ __forceinline__ float softplus_f(float x) {
  return (x > 15.f) ? x : __logf(1.f + __expf(x));
}
__device__ __forceinline__ float tanh_f(float x) {
  float e = __expf(2.f * x);
  return 1.f - 2.f / (e + 1.f);
}
__device__ __forceinline__ void publish_y(uint32_t* slot, int idx, float val, uint32_t tag) {
  unsigned short ub = __builtin_bit_cast(unsigned short, (__bf16)val);
  __hip_atomic_store(&slot[idx], (tag << 16) | (uint32_t)ub,
                     __ATOMIC_RELAXED, __HIP_MEMORY_SCOPE_AGENT);
}

__global__ void prep_kernel(const float* __restrict__ w0, const float* __restrict__ w1,
                            const float* __restrict__ w2,
                            __bf16* __restrict__ w0b, __bf16* __restrict__ w1b,
                            __bf16* __restrict__ w2b) {
  int stride = gridDim.x * blockDim.x;
  int i0 = blockIdx.x * blockDim.x + threadIdx.x;
  for (int i = i0; i < WW * HH; i += stride) w0b[i] = (__bf16)w0[i];
  for (int i = i0; i < WW * WW; i += stride) w1b[i] = (__bf16)w1[i];
  for (int i = i0; i < HD * WW; i += stride) w2b[i] = (__bf16)w2[i];
}

__global__ __launch_bounds__(256) void init_kernel(
    const float* __restrict__ ca, const float* __restrict__ iw0, const float* __restrict__ ib0,
    const float* __restrict__ iw1, const float* __restrict__ ib1,
    const float* __restrict__ iw2, const float* __restrict__ ib2,
    float* __restrict__ y0) {
  __shared__ float x0[DD];
  __shared__ float h0[WW];
  __shared__ float h1[WW];
  int b = blockIdx.x, t = threadIdx.x;
  if (t < DD) x0[t] = ca[((size_t)b * 511) * DD + t];
  __syncthreads();
  float a = ib0[t];
  for (int d = 0; d < DD; ++d) a = fmaf(x0[d], iw0[t * DD + d], a);
  h0[t] = fmaxf(a, 0.f);
  __syncthreads();
  a = ib1[t];
  for (int d = 0; d < WW; ++d) a = fmaf(h0[d], iw1[t * WW + d], a);
  h1[t] = fmaxf(a, 0.f);
  __syncthreads();
  if (t < HH) {
    a = ib2[t];
    for (int d = 0; d < WW; ++d) a = fmaf(h1[d], iw2[t * WW + d], a);
    y0[b * HH + t] = a;
  }
}

// Persistent step kernel: 256 WGs x 512 threads, loops k=0..511 internally.
__global__ __attribute__((amdgpu_flat_work_group_size(512, 512), amdgpu_waves_per_eu(2, 2)))
void step_persist(
    const __bf16* __restrict__ w0b, const __bf16* __restrict__ w1b, const __bf16* __restrict__ w2b,
    const float* __restrict__ fb0, const float* __restrict__ fb1, const float* __restrict__ fb2,
    const float* __restrict__ cbp, const float* __restrict__ ccp, const float* __restrict__ cdp,
    float* __restrict__ yA, uint32_t* __restrict__ pk)
{
  extern __shared__ __align__(16) char smem[];
  __bf16* w2l = (__bf16*)(smem + SM_W2);    // [kq=kb*4+lq][col(256)][8] = 128 KB
  __bf16* yb  = (__bf16*)(smem + SM_YB);    // 32 x PAD_Y
  __bf16* g   = (__bf16*)(smem + SM_G);     // 32 x PAD_G (g0 then g1, aliased)
  float* pbuf = (float*)(smem + SM_PBUF);   // 8 x 32

  const int tid = threadIdx.x;
  const int wv = tid >> 6;
  const int l = tid & 63;
  const int l16 = l & 15;
  const int lq = l >> 4;

  const int wid = blockIdx.x;
  const int grp = wid >> 5;
  const int j = wid & 31;
  const int rb = grp * 32;   // batch row base
  const int c0 = j * 256;    // HD col base

  // ---- one-time: stage this WG's w2 chunk into LDS, layout [kq][col][8]
  for (int blk = tid; blk < 8192; blk += 512) {
    int kq = blk >> 8, col = blk & 255;
    int kb = kq >> 2, lq2 = kq & 3;
    *(bf16x8*)&w2l[(size_t)blk * 8] =
        *(const bf16x8*)&w2b[(size_t)(c0 + col) * WW + kb * 32 + lq2 * 8];
  }

  // ---- loop-invariant biases (col-quad layout, reg dim)
  f32x4 b0r[2], b1r[2], b2r[2];
  #pragma unroll
  for (int c = 0; c < 2; ++c) {
    b0r[c] = *(const f32x4*)&fb0[wv * 32 + c * 16 + lq * 4];
    b1r[c] = *(const f32x4*)&fb1[wv * 32 + c * 16 + lq * 4];
    b2r[c] = *(const f32x4*)&fb2[c0 + wv * 32 + c * 16 + lq * 4];
  }

  // ---- per-thread deriv base offsets (rows bt*16+l16, d-slice (wv&1)*32 + c*16 + lq*4)
  size_t cb2[2];
  #pragma unroll
  for (int bt = 0; bt < 2; ++bt)
    cb2[bt] = ((size_t)(rb + bt * 16 + l16) * 511) * DD + (wv & 1) * 32 + lq * 4;

  // ---- w2 LDS fragment base (bf16 index): addr = w2base + kb*8192 + c*128
  const int w2base = lq * 2048 + (wv * 32 + l16) * 8;

  // ---- register-resident f32 state: tid<128 owns (row rb+(tid&31), h = 4j+(tid>>5))
  float yreg = 0.f;
  int myidx = 0;
  if (tid < 128) {
    int r = tid & 31, hl = tid >> 5;
    myidx = (rb + r) * HH + (4 * j + hl);
    yreg = yA[myidx];
    publish_y(pk, myidx, yreg, 1u);   // S_0 -> slot 0, tag 1
  }
  __syncthreads();   // w2l staged before first use

  for (int k = 0; k < TSTEPS; ++k) {
    const uint32_t want = (uint32_t)(k + 1);
    const uint32_t* src = pk + (size_t)(k & 1) * (BB * HH);

    // ---- prefetch w0/w1 fragments for this step (issued BEFORE the poll; the
    //      memory-clobber fence keeps them from sinking past it)
    bf16x8 w0f[4][2], w1f[8][2];
    #pragma unroll
    for (int c = 0; c < 2; ++c) {
      int col = wv * 32 + c * 16 + l16;
      #pragma unroll
      for (int kb = 0; kb < 4; ++kb)
        w0f[kb][c] = *(const bf16x8*)&w0b[col * HH + kb * 32 + lq * 8];
      #pragma unroll
      for (int kb = 0; kb < 8; ++kb)
        w1f[kb][c] = *(const bf16x8*)&w1b[col * WW + kb * 32 + lq * 8];
    }
    __asm__ __volatile__("" ::: "memory");

    // ---- poll + stage peers' y (tagged bf16 words)
    {
      uint32_t v[8];
      int ad[8];
      #pragma unroll
      for (int q = 0; q < 8; ++q) {
        int i = tid + q * 512;
        ad[q] = (rb + (i >> 7)) * HH + (i & (HH - 1));
        v[q] = __hip_atomic_load(&src[ad[q]], __ATOMIC_RELAXED, __HIP_MEMORY_SCOPE_AGENT);
      }
      int spins = 0;
      bool allok;
      do {
        allok = true;
        #pragma unroll
        for (int q = 0; q < 8; ++q) {
          if ((v[q] >> 16) != want) {
            allok = false;
            v[q] = __hip_atomic_load(&src[ad[q]], __ATOMIC_RELAXED, __HIP_MEMORY_SCOPE_AGENT);
          }
        }
        if (!allok) {
          __builtin_amdgcn_s_sleep(1);
          if (++spins > (1 << 20)) break;   // structurally impossible; bail visibly
        }
      } while (!allok);
      #pragma unroll
      for (int q = 0; q < 8; ++q) {
        int i = tid + q * 512;
        yb[(i >> 7) * PAD_Y + (i & (HH - 1))] =
            __builtin_bit_cast(__bf16, (unsigned short)(v[q] & 0xFFFFu));
      }
    }
    __syncthreads();   // A: yb ready

    // ---- gemm0 (swapped): D[w0col, brow] = w0 . y ; epilogue -> g (as g0)
    {
      f32x4 acc[2][2] = {};
      #pragma unroll
      for (int kb = 0; kb < 4; ++kb) {
        bf16x8 y0 = *(const bf16x8*)&yb[l16 * PAD_Y + kb * 32 + lq * 8];
        bf16x8 y1 = *(const bf16x8*)&yb[(16 + l16) * PAD_Y + kb * 32 + lq * 8];
        #pragma unroll
        for (int c = 0; c < 2; ++c) {
          acc[c][0] = __builtin_amdgcn_mfma_f32_16x16x32_bf16(w0f[kb][c], y0, acc[c][0], 0, 0, 0);
          acc[c][1] = __builtin_amdgcn_mfma_f32_16x16x32_bf16(w0f[kb][c], y1, acc[c][1], 0, 0, 0);
        }
      }
      #pragma unroll
      for (int c = 0; c < 2; ++c)
        #pragma unroll
        for (int bt = 0; bt < 2; ++bt) {
          bf16x4 o;
          #pragma unroll
          for (int r = 0; r < 4; ++r)
            o[r] = (__bf16)softplus_f(acc[c][bt][r] + b0r[c][r]);
          *(bf16x4*)&g[(bt * 16 + l16) * PAD_G + wv * 32 + c * 16 + lq * 4] = o;
        }
    }
    __syncthreads();   // B: g0 ready

    // ---- deriv loads (f32x4 direct from L2; consumed in gemm2, latency hidden by gemm1)
    f32x4 dv_[2][2];
    {
      size_t ko = (size_t)((k <= 510) ? k : 510) * DD;
      #pragma unroll
      for (int bt = 0; bt < 2; ++bt)
        #pragma unroll
        for (int c = 0; c < 2; ++c) {
          size_t off = cb2[bt] + ko + c * 16;
          dv_[bt][c] = *(const f32x4*)&cbp[off];
          if (k == 511) {
            f32x4 cc = *(const f32x4*)&ccp[off];
            f32x4 dd = *(const f32x4*)&cdp[off];
            #pragma unroll
            for (int r = 0; r < 4; ++r)
              dv_[bt][c][r] += 2.f * cc[r] + 3.f * dd[r];
          }
        }
    }

    // ---- gemm1 (swapped): reads g (g0)
    f32x4 acc1[2][2] = {};
    {
      #pragma unroll
      for (int kb = 0; kb < 8; ++kb) {
        bf16x8 a0 = *(const bf16x8*)&g[l16 * PAD_G + kb * 32 + lq * 8];
        bf16x8 a1 = *(const bf16x8*)&g[(16 + l16) * PAD_G + kb * 32 + lq * 8];
        #pragma unroll
        for (int c = 0; c < 2; ++c) {
          acc1[c][0] = __builtin_amdgcn_mfma_f32_16x16x32_bf16(w1f[kb][c], a0, acc1[c][0], 0, 0, 0);
          acc1[c][1] = __builtin_amdgcn_mfma_f32_16x16x32_bf16(w1f[kb][c], a1, acc1[c][1], 0, 0, 0);
        }
      }
    }
    __syncthreads();   // C: all g0 reads done (g about to be overwritten)

    // ---- gemm1 epilogue: writes g (as g1)
    #pragma unroll
    for (int c = 0; c < 2; ++c)
      #pragma unroll
      for (int bt = 0; bt < 2; ++bt) {
        bf16x4 o;
        #pragma unroll
        for (int r = 0; r < 4; ++r)
          o[r] = (__bf16)softplus_f(acc1[c][bt][r] + b1r[c][r]);
        *(bf16x4*)&g[(bt * 16 + l16) * PAD_G + wv * 32 + c * 16 + lq * 4] = o;
      }
    __syncthreads();   // D: g1 ready

    // ---- gemm2 chunk (swapped, w2 from LDS) + tanh + d-contraction
    {
      f32x4 acc[2][2] = {};
      #pragma unroll
      for (int kb = 0; kb < 8; ++kb) {
        bf16x8 a0 = *(const bf16x8*)&g[l16 * PAD_G + kb * 32 + lq * 8];
        bf16x8 a1 = *(const bf16x8*)&g[(16 + l16) * PAD_G + kb * 32 + lq * 8];
        #pragma unroll
        for (int c = 0; c < 2; ++c) {
          bf16x8 wf = *(const bf16x8*)&w2l[w2base + kb * 8192 + c * 128];
          acc[c][0] = __builtin_amdgcn_mfma_f32_16x16x32_bf16(wf, a0, acc[c][0], 0, 0, 0);
          acc[c][1] = __builtin_amdgcn_mfma_f32_16x16x32_bf16(wf, a1, acc[c][1], 0, 0, 0);
        }
      }
      // lane holds: batch row = bt*16+l16; d = (wv&1)*32 + c*16 + lq*4 + r
      #pragma unroll
      for (int bt = 0; bt < 2; ++bt) {
        float p = 0.f;
        #pragma unroll
        for (int c = 0; c < 2; ++c) {
          #pragma unroll
          for (int r = 0; r < 4; ++r) {
            float f = tanh_f(acc[c][bt][r] + b2r[c][r]);
            p = fmaf(f, dv_[bt][c][r], p);
          }
        }
        p += __shfl_xor(p, 16);
        p += __shfl_xor(p, 32);
        if (l < 16) pbuf[wv * 32 + bt * 16 + l] = p;
      }
    }
    __syncthreads();   // E: pbuf ready

    // ---- combine wave pairs (d halves), update register state, publish
    if (tid < 128) {
      int hl = tid >> 5, r = tid & 31;
      yreg += pbuf[(2 * hl) * 32 + r] + pbuf[(2 * hl + 1) * 32 + r];
      publish_y(pk + (size_t)((k + 1) & 1) * (BB * HH), myidx, yreg, (uint32_t)(k + 2));
    }
    __syncthreads();   // F: pbuf/yb safe to reuse next step
  }

  if (tid < 128) yA[myidx] = yreg;
}

__global__ __launch_bounds__(256) void final_kernel(const float* __restrict__ y,
                                                    const float* __restrict__ lw,
                                                    const float* __restrict__ lb,
                                                    float* __restrict__ out) {
  int b = threadIdx.x;
  float a = lb[0];
  for (int h = 0; h < HH; ++h) a = fmaf(y[b * HH + h], lw[h], a);
  out[b] = 1.f / (1.f + __expf(-a));
}

extern "C" void kernel_launch(void* const* d_in, const int* in_sizes, int n_in,
                              void* d_out, int out_size, void* d_ws, size_t ws_size,
                              hipStream_t stream) {
  const float* cdp = (const float*)d_in[1];
  const float* ccp = (const float*)d_in[2];
  const float* cbp = (const float*)d_in[3];
  const float* cap = (const float*)d_in[4];
  const float* iw0 = (const float*)d_in[5];
  const float* ib0 = (const float*)d_in[6];
  const float* iw1 = (const float*)d_in[7];
  const float* ib1 = (const float*)d_in[8];
  const float* iw2 = (const float*)d_in[9];
  const float* ib2 = (const float*)d_in[10];
  const float* fw0 = (const float*)d_in[11];
  const float* fb0 = (const float*)d_in[12];
  const float* fw1 = (const float*)d_in[13];
  const float* fb1 = (const float*)d_in[14];
  const float* fw2 = (const float*)d_in[15];
  const float* fb2 = (const float*)d_in[16];
  const float* lw  = (const float*)d_in[17];
  const float* lb  = (const float*)d_in[18];

  char* ws = (char*)d_ws;
  __bf16* w0b = (__bf16*)(ws);                              // 64 KB
  __bf16* w1b = (__bf16*)(ws + 65536);                      // 128 KB
  __bf16* w2b = (__bf16*)(ws + 65536 + 131072);             // 4 MB
  float* yA = (float*)(ws + 65536 + 131072 + 4194304);      // 128 KB
  uint32_t* pk = (uint32_t*)(ws + 65536 + 131072 + 4194304 + 131072);  // 256 KB (2 slots)

  hipMemsetAsync(pk, 0, 2 * BB * HH * sizeof(uint32_t), stream);
  prep_kernel<<<512, 256, 0, stream>>>(fw0, fw1, fw2, w0b, w1b, w2b);
  init_kernel<<<BB, 256, 0, stream>>>(cap, iw0, ib0, iw1, ib1, iw2, ib2, yA);
  step_persist<<<256, 512, SM_TOT, stream>>>(w0b, w1b, w2b, fb0, fb1, fb2,
                                             cbp, ccp, cdp, yA, pk);
  final_kernel<<<1, 256, 0, stream>>>(yA, lw, lb, (float*)d_out);

  (void)in_sizes; (void)n_in; (void)out_size; (void)ws_size;
}